// Round 14
// baseline (50.917 us; speedup 1.0000x reference)
//
#include <hip/hip_runtime.h>

#define NTILES_X 65          // ceil(1026/16)
#define NTILES   (65*65)     // 4225
#define OHW      1026
#define NCHUNK   32
#define NBLK     2048        // 8 blocks/CU co-resident (64 VGPR, 16.4 KB LDS)
#define NXCD     8
#define BAND     529         // ceil(NTILES/NXCD)

typedef unsigned int  uint;
typedef unsigned short ushort;
typedef float  floatx16 __attribute__((ext_vector_type(16)));
typedef __bf16 bf16x8   __attribute__((ext_vector_type(8)));

__device__ __forceinline__ uint pk2f(float a, float b) {
    ushort lo = __builtin_bit_cast(ushort, (__bf16)a);
    ushort hi = __builtin_bit_cast(ushort, (__bf16)b);
    return (uint)lo | ((uint)hi << 16);
}
__device__ __forceinline__ bf16x8 frag_of(uint a, uint b, uint c, uint d) {
    uint4 u = make_uint4(a, b, c, d);
    return __builtin_bit_cast(bf16x8, u);
}
// k -> element offset in a [3][18][18] tile  (k = ic*9 + ky*3 + kx)
__device__ __forceinline__ constexpr int koff_of(int k) {
    return (k / 9) * 324 + ((k % 9) / 3) * 18 + (k % 3);
}
// one patch-frag u16: slot k = (h ? kb : ka); ka,kb compile-time (kb = ka+8).
// k==27 is the bias slot (B=1.0); k>27 -> 0.
__device__ __forceinline__ uint bslot(const ushort* buf, int base, int h, int ka, int kb) {
    if (kb < 27) {
        int off = h ? koff_of(kb) : koff_of(ka);
        return (uint)buf[base + off];
    } else if (ka < 27) {
        uint cst = (kb == 27) ? 0x3F80u : 0u;
        uint rd  = (uint)buf[base + koff_of(ka)];
        return h ? cst : rd;
    } else {
        uint ca  = (ka == 27) ? 0x3F80u : 0u;
        uint cb2 = (kb == 27) ? 0x3F80u : 0u;
        return h ? cb2 : ca;
    }
}

// ---------------------------------------------------------------------------
// Kernel 1: conv1 implicit-GEMM MFMA + gram from conv D-regs, dbuf staging.
// LDS: single 16 KB arena — sInB (3.9 KB, tile loop) aliases gep (16 KB,
// epilogue only; barrier-separated). 16.4 KB + 64 VGPR -> 8 blocks/CU.
// ---------------------------------------------------------------------------
__global__ __launch_bounds__(256, 4) void k_conv_gram(
    const float* __restrict__ x,   // [3][1024][1024]
    const float* __restrict__ w1,  // [32][3][3][3]
    const float* __restrict__ b1,  // [32]
    float* __restrict__ partial,   // [NBLK][1024]
    int nblk)
{
    __shared__ __align__(16) float smem[4096];       // 16 KB arena
    ushort* sIn0 = (ushort*)smem;                    // [976] buf 0
    ushort* sIn1 = (ushort*)smem + 976;              // [976] buf 1
    float*  gep  = smem;                             // epilogue alias

    const int t    = threadIdx.x;
    const int wv   = t >> 6;
    const int lane = t & 63;
    const int h    = lane >> 5;
    const int c    = lane & 31;

    // ---- weight(+bias) fragments, built once ----
    const float b1c = b1[c];
    uint wu0[4], wu1[4];
#pragma unroll
    for (int q = 0; q < 4; ++q) {
        {
            int k0 = h * 8 + 2 * q;
            wu0[q] = pk2f(w1[c * 27 + k0], w1[c * 27 + k0 + 1]);
        }
        {
            int k0 = 16 + h * 8 + 2 * q, k1 = k0 + 1;
            float r0 = w1[c * 27 + (k0 < 27 ? k0 : 26)];
            float r1 = w1[c * 27 + (k1 < 27 ? k1 : 26)];
            float v0 = (k0 < 27) ? r0 : (k0 == 27 ? b1c : 0.f);
            float v1 = (k1 < 27) ? r1 : (k1 == 27 ? b1c : 0.f);
            wu1[q] = pk2f(v0, v1);
        }
    }

    floatx16 gacc;
#pragma unroll
    for (int i = 0; i < 16; ++i) gacc[i] = 0.f;

    const int xcd    = blockIdx.x & (NXCD - 1);
    const int lb     = blockIdx.x >> 3;
    const int nb_per = nblk >> 3;
    const int tstart = xcd * BAND;
    const int tend   = (tstart + BAND < NTILES) ? tstart + BAND : NTILES;

    auto loadregs = [&](int tile, float* v) {
        const int ty = tile / NTILES_X;
        const int tx = tile - ty * NTILES_X;
        const int by = ty * 16, bx = tx * 16;
        const bool interior = (ty >= 1) & (ty <= 62) & (tx >= 1) & (tx <= 62);
#pragma unroll
        for (int j = 0; j < 4; ++j) {
            const int i = t + 256 * j;
            if (j == 3 && i >= 972) { v[j] = 0.f; continue; }
            int ic = i / 324, rem = i - ic * 324, r = rem / 18, cc = rem - r * 18;
            if (interior) {
                v[j] = x[ic * 1048576 + (by - 2 + r) * 1024 + (bx - 2 + cc)];
            } else {
                int iy = by - 2 + r, ix = bx - 2 + cc;
                v[j] = ((unsigned)iy < 1024u && (unsigned)ix < 1024u)
                         ? x[ic * 1048576 + iy * 1024 + ix] : 0.f;
            }
        }
    };
    auto writebuf = [&](ushort* buf, const float* v) {
#pragma unroll
        for (int j = 0; j < 4; ++j) {
            const int i = t + 256 * j;
            if (j == 3 && i >= 972) continue;
            buf[i] = __builtin_bit_cast(ushort, (__bf16)v[j]);
        }
    };

    int tile = tstart + lb;
    int cur  = 0;
    {
        float v[4];
        loadregs(tile, v);
        writebuf(sIn0, v);
    }
    __syncthreads();

    for (; tile < tend; ) {
        const int nxt = tile + nb_per;
        const bool hasNext = nxt < tend;
        float vn[4];
        if (hasNext) loadregs(nxt, vn);

        {
            const int ty = tile / NTILES_X;
            const int tx = tile - ty * NTILES_X;
            const int by = ty * 16, bx = tx * 16;
            const bool needmask = (ty == 64) | (tx == 64);
            const ushort* bufp = cur ? sIn1 : sIn0;

#pragma unroll
            for (int e = 0; e < 2; ++e) {
                const int cb   = 2 * wv + e;
                const int base = (cb * 2 + (c >> 4)) * 18 + (c & 15);

                floatx16 cacc;
#pragma unroll
                for (int i = 0; i < 16; ++i) cacc[i] = 0.f;

                uint bu[4];
#pragma unroll
                for (int q = 0; q < 4; ++q) {
                    uint lo = bslot(bufp, base, h, 2*q,     2*q + 8);
                    uint hi = bslot(bufp, base, h, 2*q + 1, 2*q + 9);
                    bu[q] = lo | (hi << 16);
                }
                cacc = __builtin_amdgcn_mfma_f32_32x32x16_bf16(
                    frag_of(bu[0], bu[1], bu[2], bu[3]),
                    frag_of(wu0[0], wu0[1], wu0[2], wu0[3]), cacc, 0, 0, 0);
#pragma unroll
                for (int q = 0; q < 4; ++q) {
                    uint lo = bslot(bufp, base, h, 16 + 2*q,     16 + 2*q + 8);
                    uint hi = bslot(bufp, base, h, 16 + 2*q + 1, 16 + 2*q + 9);
                    bu[q] = lo | (hi << 16);
                }
                cacc = __builtin_amdgcn_mfma_f32_32x32x16_bf16(
                    frag_of(bu[0], bu[1], bu[2], bu[3]),
                    frag_of(wu1[0], wu1[1], wu1[2], wu1[3]), cacc, 0, 0, 0);

                uint pa[4], pb[4];
#pragma unroll
                for (int q2 = 0; q2 < 4; ++q2) {
                    pa[q2] = pk2f(cacc[2*q2],     cacc[2*q2 + 1]);
                    pb[q2] = pk2f(cacc[8 + 2*q2], cacc[8 + 2*q2 + 1]);
                }
                if (needmask) {
                    const uint rA = (uint)((by + 2*cb)     < OHW);
                    const uint rB = (uint)((by + 2*cb + 1) < OHW);
#pragma unroll
                    for (int q2 = 0; q2 < 4; ++q2) {
                        const int q  = q2 >> 1, mm = 2 * (q2 & 1);
                        const uint x0 = (uint)((bx + 8*q + 4*h + mm)     < OHW);
                        const uint x1 = (uint)((bx + 8*q + 4*h + mm + 1) < OHW);
                        pa[q2] &= ((rA & x0) ? 0x0000FFFFu : 0u) | ((rA & x1) ? 0xFFFF0000u : 0u);
                        pb[q2] &= ((rB & x0) ? 0x0000FFFFu : 0u) | ((rB & x1) ? 0xFFFF0000u : 0u);
                    }
                }
                bf16x8 fa = frag_of(pa[0], pa[1], pa[2], pa[3]);
                bf16x8 fb = frag_of(pb[0], pb[1], pb[2], pb[3]);
                gacc = __builtin_amdgcn_mfma_f32_32x32x16_bf16(fa, fa, gacc, 0, 0, 0);
                gacc = __builtin_amdgcn_mfma_f32_32x32x16_bf16(fb, fb, gacc, 0, 0, 0);
            }
        }

        if (hasNext) writebuf(cur ? sIn0 : sIn1, vn);
        __syncthreads();    // also separates last sInB read from gep reuse
        cur ^= 1;
        tile = nxt;
    }

    // ---- epilogue: C-layout scatter (gep aliases sInB; loop-final barrier
    // guarantees all tile reads are done), cross-wave reduce, store ----
#pragma unroll
    for (int r = 0; r < 16; ++r) {
        const int row = (r & 3) + 8 * (r >> 2) + 4 * h;
        gep[wv * 1024 + row * 32 + c] = gacc[r];
    }
    __syncthreads();
    {
        const int e = t * 4;
        float s[4] = {0.f, 0.f, 0.f, 0.f};
#pragma unroll
        for (int w = 0; w < 4; ++w) {
            float v[4];
            *(float4*)v = *(const float4*)&gep[w * 1024 + e];
#pragma unroll
            for (int j = 0; j < 4; ++j) s[j] += v[j];
        }
        *(float4*)&partial[(size_t)blockIdx.x * 1024 + e] = *(float4*)s;
    }
}

// ---------------------------------------------------------------------------
// Kernel 2: reduce NBLK partials -> NCHUNK partials. 32768 threads, coalesced.
// ---------------------------------------------------------------------------
__global__ __launch_bounds__(256) void k_reduce(
    const float* __restrict__ partial, float* __restrict__ partial2, int nblk)
{
    const int gt    = blockIdx.x * 256 + threadIdx.x;
    const int e     = gt & 1023;
    const int chunk = gt >> 10;
    float s = 0.f;
    for (int b = chunk; b < nblk; b += NCHUNK) s += partial[(size_t)b * 1024 + e];
    partial2[chunk * 1024 + e] = s;
}

// ---------------------------------------------------------------------------
// Kernel 3: fused tail — 32 blocks; each redundantly computes mid phase
// (P2 fold, conv2, BN1) then its own channel's conv3+BN2+mean (R13-proven).
// ---------------------------------------------------------------------------
__global__ __launch_bounds__(256) void k_tail2(
    const float* __restrict__ partial2,   // [NCHUNK][1024]
    const float* __restrict__ w2, const float* __restrict__ b2,
    const float* __restrict__ g2, const float* __restrict__ bt2,
    const float* __restrict__ w3, const float* __restrict__ b3,
    const float* __restrict__ g3, const float* __restrict__ bt3,
    float* __restrict__ out)              // [32]
{
    __shared__ float G_pad[36 * 36];      // zero halo 2
    __shared__ float y1[16 * 289];
    __shared__ float y1p[16 * 21 * 21];   // BN1+ReLU, zero halo 2
    __shared__ float y2L[256];
    __shared__ float m1[16], r1[16];
    __shared__ float sw2[144], sp2[48];

    const int t  = threadIdx.x;
    const int oc = blockIdx.x;

    float gv[4] = {0.f, 0.f, 0.f, 0.f};
#pragma unroll
    for (int k = 0; k < NCHUNK; ++k) {
        float v[4];
        *(float4*)v = *(const float4*)&partial2[k * 1024 + t * 4];
#pragma unroll
        for (int j = 0; j < 4; ++j) gv[j] += v[j];
    }

    for (int i = t; i < 1296; i += 256) G_pad[i] = 0.f;
    for (int i = t; i < 7056; i += 256) y1p[i] = 0.f;
    if (t < 144) sw2[t] = w2[t];
    if (t >= 160 && t < 176)      sp2[t - 160]      = b2[t - 160];
    else if (t >= 176 && t < 192) sp2[t - 160]      = g2[t - 176];
    else if (t >= 192 && t < 208) sp2[t - 160]      = bt2[t - 192];
    __syncthreads();

#pragma unroll
    for (int j = 0; j < 4; ++j) {
        const int e = t * 4 + j;
        G_pad[((e >> 5) + 2) * 36 + (e & 31) + 2] = gv[j];
    }
    __syncthreads();

    for (int idx = t; idx < 16 * 289; idx += 256) {
        const int c2 = idx / 289;
        const int r  = idx - c2 * 289;
        const int oy = r / 17, ox = r - (r / 17) * 17;
        const float* gp = &G_pad[(2 * oy) * 36 + 2 * ox];
        const float* wr = &sw2[c2 * 9];
        float s = sp2[c2];
#pragma unroll
        for (int ky = 0; ky < 3; ++ky)
#pragma unroll
            for (int kx = 0; kx < 3; ++kx)
                s = fmaf(gp[ky * 36 + kx], wr[ky * 3 + kx], s);
        y1[idx] = s;
    }
    __syncthreads();

    {
        const int lane = t & 63;
        const int ch   = (t >> 6) * 4 + (lane >> 4);
        const int j    = lane & 15;
        float s = 0.f, ss = 0.f;
        for (int i = j; i < 289; i += 16) {
            float v = y1[ch * 289 + i];
            s += v; ss += v * v;
        }
#pragma unroll
        for (int o = 8; o; o >>= 1) { s += __shfl_xor(s, o); ss += __shfl_xor(ss, o); }
        if (j == 0) {
            float m = s * (1.f / 289.f);
            float var = ss * (1.f / 289.f) - m * m;
            m1[ch] = m;
            r1[ch] = rsqrtf(var + 1e-5f);
        }
    }
    __syncthreads();

    for (int idx = t; idx < 16 * 289; idx += 256) {
        const int c2 = idx / 289;
        const int r  = idx - c2 * 289;
        const int oy = r / 17, ox = r - (r / 17) * 17;
        float v = (y1[idx] - m1[c2]) * r1[c2] * sp2[16 + c2] + sp2[32 + c2];
        y1p[c2 * 441 + (oy + 2) * 21 + ox + 2] = v > 0.f ? v : 0.f;
    }
    if (t >= 100 && t < 128) y2L[t] = 0.f;
    __syncthreads();

    {
        const int grp = t >> 7;
        const int px  = t & 127;
        if (px < 100) {
            const int oy = px / 10, ox = px - 10 * (px / 10);
            const float* wr = w3 + oc * 144 + grp * 72;
            float a0 = 0.f, a1 = 0.f, a2 = 0.f;
#pragma unroll
            for (int ic8 = 0; ic8 < 8; ++ic8) {
                const int ic = grp * 8 + ic8;
                const float* yi = &y1p[ic * 441 + (2 * oy) * 21 + 2 * ox];
                const float* wi = wr + ic8 * 9;
#pragma unroll
                for (int kx = 0; kx < 3; ++kx) {
                    a0 = fmaf(yi[kx],      wi[kx],     a0);
                    a1 = fmaf(yi[21 + kx], wi[3 + kx], a1);
                    a2 = fmaf(yi[42 + kx], wi[6 + kx], a2);
                }
            }
            y2L[grp * 128 + px] = (a0 + a1) + a2;
        }
    }
    __syncthreads();

    if (t < 100) y2L[t] = y2L[t] + y2L[128 + t] + b3[oc];
    __syncthreads();

    if (t < 64) {
        const float x0 = y2L[t], x1 = y2L[t + 64];
        float s = x0 + x1, ss = x0 * x0 + x1 * x1;
#pragma unroll
        for (int o = 32; o; o >>= 1) { s += __shfl_xor(s, o); ss += __shfl_xor(ss, o); }
        const float m   = s * 0.01f;
        const float var = ss * 0.01f - m * m;
        const float rs  = rsqrtf(var + 1e-5f);
        const float gg  = g3[oc], bb = bt3[oc];
        float a = 0.f;
        if (t < 100) { float f = (x0 - m) * rs * gg + bb; a += f > 0.f ? f : 0.f; }
        if (t < 36)  { float f = (x1 - m) * rs * gg + bb; a += f > 0.f ? f : 0.f; }
#pragma unroll
        for (int o = 32; o; o >>= 1) a += __shfl_xor(a, o);
        if (t == 0) out[oc] = a * 0.01f;
    }
}

// ---------------------------------------------------------------------------
extern "C" void kernel_launch(void* const* d_in, const int* in_sizes, int n_in,
                              void* d_out, int out_size, void* d_ws, size_t ws_size,
                              hipStream_t stream)
{
    const float* x   = (const float*)d_in[0];
    const float* w1  = (const float*)d_in[1];
    const float* b1  = (const float*)d_in[2];
    const float* w2  = (const float*)d_in[3];
    const float* b2  = (const float*)d_in[4];
    const float* g2  = (const float*)d_in[5];
    const float* bt2 = (const float*)d_in[6];
    const float* w3  = (const float*)d_in[7];
    const float* b3  = (const float*)d_in[8];
    const float* g3  = (const float*)d_in[9];
    const float* bt3 = (const float*)d_in[10];

    size_t cap = ws_size / 4096;               // 1024-float slots available
    int nblk = NBLK;
    if ((size_t)(nblk + NCHUNK) > cap) nblk = ((int)cap - NCHUNK) & ~7;
    if (nblk > NBLK) nblk = NBLK;
    if (nblk < 256) nblk = 256;

    float* P   = (float*)d_ws;                  // [nblk][1024]
    float* P2  = P + (size_t)nblk * 1024;       // [NCHUNK][1024]
    float* out = (float*)d_out;

    k_conv_gram<<<nblk, 256, 0, stream>>>(x, w1, b1, P, nblk);
    k_reduce<<<128, 256, 0, stream>>>(P, P2, nblk);
    k_tail2<<<32, 256, 0, stream>>>(P2, w2, b2, g2, bt2, w3, b3, g3, bt3, out);
}

// Round 15
// 42.519 us; speedup vs baseline: 1.1975x; 1.1975x over previous
//
#include <hip/hip_runtime.h>

#define NTILES_X 65          // ceil(1026/16)
#define NTILES   (65*65)     // 4225
#define OHW      1026
#define NCHUNK   32
#define NBLK     1024        // 4 blocks/CU x 512 thr = 32 waves/CU (max)
#define NXCD     8
#define BAND     529         // ceil(NTILES/NXCD)

typedef unsigned int  uint;
typedef unsigned short ushort;
typedef float  floatx16 __attribute__((ext_vector_type(16)));
typedef __bf16 bf16x8   __attribute__((ext_vector_type(8)));

__device__ __forceinline__ uint pk2f(float a, float b) {
    ushort lo = __builtin_bit_cast(ushort, (__bf16)a);
    ushort hi = __builtin_bit_cast(ushort, (__bf16)b);
    return (uint)lo | ((uint)hi << 16);
}
__device__ __forceinline__ bf16x8 frag_of(uint a, uint b, uint c, uint d) {
    uint4 u = make_uint4(a, b, c, d);
    return __builtin_bit_cast(bf16x8, u);
}
// k -> element offset in a [3][18][18] tile  (k = ic*9 + ky*3 + kx)
__device__ __forceinline__ constexpr int koff_of(int k) {
    return (k / 9) * 324 + ((k % 9) / 3) * 18 + (k % 3);
}
// one patch-frag u16: slot k = (h ? kb : ka); ka,kb compile-time (kb = ka+8).
// k==27 is the bias slot (B=1.0); k>27 -> 0.
__device__ __forceinline__ uint bslot(const ushort* buf, int base, int h, int ka, int kb) {
    if (kb < 27) {
        int off = h ? koff_of(kb) : koff_of(ka);
        return (uint)buf[base + off];
    } else if (ka < 27) {
        uint cst = (kb == 27) ? 0x3F80u : 0u;
        uint rd  = (uint)buf[base + koff_of(ka)];
        return h ? cst : rd;
    } else {
        uint ca  = (ka == 27) ? 0x3F80u : 0u;
        uint cb2 = (kb == 27) ? 0x3F80u : 0u;
        return h ? cb2 : ca;
    }
}

// ---------------------------------------------------------------------------
// Kernel 1: conv1 implicit-GEMM MFMA + gram from conv D-regs, dbuf staging.
// 512 threads/block: 8 waves, each owns ONE 32-px col-block per tile (no e
// loop). 4 blocks/CU x 8 waves = 8 waves/SIMD (hw max) with the SAME
// per-block pipeline depth (~4 tiles) — fixes R14's confound (occupancy via
// more blocks doubled per-block fixed costs; via more waves it doesn't).
// LDS arena 32 KB: sInB dbuf (3.9 KB, loop) aliases gep (32 KB, epilogue).
// ---------------------------------------------------------------------------
__global__ __launch_bounds__(512, 4) void k_conv_gram(
    const float* __restrict__ x,   // [3][1024][1024]
    const float* __restrict__ w1,  // [32][3][3][3]
    const float* __restrict__ b1,  // [32]
    float* __restrict__ partial,   // [NBLK][1024]
    int nblk)
{
    __shared__ __align__(16) float smem[8192];       // 32 KB arena
    ushort* sIn0 = (ushort*)smem;                    // [976] buf 0
    ushort* sIn1 = (ushort*)smem + 976;              // [976] buf 1
    float*  gep  = smem;                             // epilogue alias

    const int t    = threadIdx.x;        // 0..511
    const int wv   = t >> 6;             // 0..7  == col-block cb
    const int lane = t & 63;
    const int h    = lane >> 5;
    const int c    = lane & 31;

    // ---- weight(+bias) fragments, built once ----
    const float b1c = b1[c];
    uint wu0[4], wu1[4];
#pragma unroll
    for (int q = 0; q < 4; ++q) {
        {
            int k0 = h * 8 + 2 * q;
            wu0[q] = pk2f(w1[c * 27 + k0], w1[c * 27 + k0 + 1]);
        }
        {
            int k0 = 16 + h * 8 + 2 * q, k1 = k0 + 1;
            float r0 = w1[c * 27 + (k0 < 27 ? k0 : 26)];
            float r1 = w1[c * 27 + (k1 < 27 ? k1 : 26)];
            float v0 = (k0 < 27) ? r0 : (k0 == 27 ? b1c : 0.f);
            float v1 = (k1 < 27) ? r1 : (k1 == 27 ? b1c : 0.f);
            wu1[q] = pk2f(v0, v1);
        }
    }

    floatx16 gacc;
#pragma unroll
    for (int i = 0; i < 16; ++i) gacc[i] = 0.f;

    const int xcd    = blockIdx.x & (NXCD - 1);
    const int lb     = blockIdx.x >> 3;          // 0..127
    const int nb_per = nblk >> 3;                // 128
    const int tstart = xcd * BAND;
    const int tend   = (tstart + BAND < NTILES) ? tstart + BAND : NTILES;

    auto loadregs = [&](int tile, float* v) {
        const int ty = tile / NTILES_X;
        const int tx = tile - ty * NTILES_X;
        const int by = ty * 16, bx = tx * 16;
        const bool interior = (ty >= 1) & (ty <= 62) & (tx >= 1) & (tx <= 62);
#pragma unroll
        for (int j = 0; j < 2; ++j) {
            const int i = t + 512 * j;
            if (j == 1 && i >= 972) { v[j] = 0.f; continue; }
            int ic = i / 324, rem = i - ic * 324, r = rem / 18, cc = rem - r * 18;
            if (interior) {
                v[j] = x[ic * 1048576 + (by - 2 + r) * 1024 + (bx - 2 + cc)];
            } else {
                int iy = by - 2 + r, ix = bx - 2 + cc;
                v[j] = ((unsigned)iy < 1024u && (unsigned)ix < 1024u)
                         ? x[ic * 1048576 + iy * 1024 + ix] : 0.f;
            }
        }
    };
    auto writebuf = [&](ushort* buf, const float* v) {
#pragma unroll
        for (int j = 0; j < 2; ++j) {
            const int i = t + 512 * j;
            if (j == 1 && i >= 972) continue;
            buf[i] = __builtin_bit_cast(ushort, (__bf16)v[j]);
        }
    };

    int tile = tstart + lb;
    int cur  = 0;
    {
        float v[2];
        loadregs(tile, v);
        writebuf(sIn0, v);
    }
    __syncthreads();

    for (; tile < tend; ) {
        const int nxt = tile + nb_per;
        const bool hasNext = nxt < tend;
        float vn[2];
        if (hasNext) loadregs(nxt, vn);

        {
            const int ty = tile / NTILES_X;
            const int tx = tile - ty * NTILES_X;
            const int by = ty * 16, bx = tx * 16;
            const bool needmask = (ty == 64) | (tx == 64);
            const ushort* bufp = cur ? sIn1 : sIn0;

            const int cb   = wv;                       // this wave's col-block
            const int base = (cb * 2 + (c >> 4)) * 18 + (c & 15);

            floatx16 cacc;
#pragma unroll
            for (int i = 0; i < 16; ++i) cacc[i] = 0.f;

            uint bu[4];
#pragma unroll
            for (int q = 0; q < 4; ++q) {
                uint lo = bslot(bufp, base, h, 2*q,     2*q + 8);
                uint hi = bslot(bufp, base, h, 2*q + 1, 2*q + 9);
                bu[q] = lo | (hi << 16);
            }
            cacc = __builtin_amdgcn_mfma_f32_32x32x16_bf16(
                frag_of(bu[0], bu[1], bu[2], bu[3]),
                frag_of(wu0[0], wu0[1], wu0[2], wu0[3]), cacc, 0, 0, 0);
#pragma unroll
            for (int q = 0; q < 4; ++q) {
                uint lo = bslot(bufp, base, h, 16 + 2*q,     16 + 2*q + 8);
                uint hi = bslot(bufp, base, h, 16 + 2*q + 1, 16 + 2*q + 9);
                bu[q] = lo | (hi << 16);
            }
            cacc = __builtin_amdgcn_mfma_f32_32x32x16_bf16(
                frag_of(bu[0], bu[1], bu[2], bu[3]),
                frag_of(wu1[0], wu1[1], wu1[2], wu1[3]), cacc, 0, 0, 0);

            uint pa[4], pb[4];
#pragma unroll
            for (int q2 = 0; q2 < 4; ++q2) {
                pa[q2] = pk2f(cacc[2*q2],     cacc[2*q2 + 1]);
                pb[q2] = pk2f(cacc[8 + 2*q2], cacc[8 + 2*q2 + 1]);
            }
            if (needmask) {
                const uint rA = (uint)((by + 2*cb)     < OHW);
                const uint rB = (uint)((by + 2*cb + 1) < OHW);
#pragma unroll
                for (int q2 = 0; q2 < 4; ++q2) {
                    const int q  = q2 >> 1, mm = 2 * (q2 & 1);
                    const uint x0 = (uint)((bx + 8*q + 4*h + mm)     < OHW);
                    const uint x1 = (uint)((bx + 8*q + 4*h + mm + 1) < OHW);
                    pa[q2] &= ((rA & x0) ? 0x0000FFFFu : 0u) | ((rA & x1) ? 0xFFFF0000u : 0u);
                    pb[q2] &= ((rB & x0) ? 0x0000FFFFu : 0u) | ((rB & x1) ? 0xFFFF0000u : 0u);
                }
            }
            bf16x8 fa = frag_of(pa[0], pa[1], pa[2], pa[3]);
            bf16x8 fb = frag_of(pb[0], pb[1], pb[2], pb[3]);
            gacc = __builtin_amdgcn_mfma_f32_32x32x16_bf16(fa, fa, gacc, 0, 0, 0);
            gacc = __builtin_amdgcn_mfma_f32_32x32x16_bf16(fb, fb, gacc, 0, 0, 0);
        }

        if (hasNext) writebuf(cur ? sIn0 : sIn1, vn);
        __syncthreads();    // next buf ready; also fences before gep reuse
        cur ^= 1;
        tile = nxt;
    }

    // ---- epilogue: scatter 8 wave-grams, cross-wave reduce, store ----
#pragma unroll
    for (int r = 0; r < 16; ++r) {
        const int row = (r & 3) + 8 * (r >> 2) + 4 * h;
        gep[wv * 1024 + row * 32 + c] = gacc[r];
    }
    __syncthreads();
    if (t < 256) {
        const int e = t * 4;
        float s[4] = {0.f, 0.f, 0.f, 0.f};
#pragma unroll
        for (int w = 0; w < 8; ++w) {
            float v[4];
            *(float4*)v = *(const float4*)&gep[w * 1024 + e];
#pragma unroll
            for (int j = 0; j < 4; ++j) s[j] += v[j];
        }
        *(float4*)&partial[(size_t)blockIdx.x * 1024 + e] = *(float4*)s;
    }
}

// ---------------------------------------------------------------------------
// Kernel 2: reduce NBLK partials -> NCHUNK partials. 32768 threads, coalesced.
// ---------------------------------------------------------------------------
__global__ __launch_bounds__(256) void k_reduce(
    const float* __restrict__ partial, float* __restrict__ partial2, int nblk)
{
    const int gt    = blockIdx.x * 256 + threadIdx.x;
    const int e     = gt & 1023;
    const int chunk = gt >> 10;
    float s = 0.f;
    for (int b = chunk; b < nblk; b += NCHUNK) s += partial[(size_t)b * 1024 + e];
    partial2[chunk * 1024 + e] = s;
}

// ---------------------------------------------------------------------------
// Kernel 3: fused tail — 32 blocks; each redundantly computes mid phase
// (P2 fold, conv2, BN1) then its own channel's conv3+BN2+mean (R13-proven).
// ---------------------------------------------------------------------------
__global__ __launch_bounds__(256) void k_tail2(
    const float* __restrict__ partial2,   // [NCHUNK][1024]
    const float* __restrict__ w2, const float* __restrict__ b2,
    const float* __restrict__ g2, const float* __restrict__ bt2,
    const float* __restrict__ w3, const float* __restrict__ b3,
    const float* __restrict__ g3, const float* __restrict__ bt3,
    float* __restrict__ out)              // [32]
{
    __shared__ float G_pad[36 * 36];      // zero halo 2
    __shared__ float y1[16 * 289];
    __shared__ float y1p[16 * 21 * 21];   // BN1+ReLU, zero halo 2
    __shared__ float y2L[256];
    __shared__ float m1[16], r1[16];
    __shared__ float sw2[144], sp2[48];

    const int t  = threadIdx.x;
    const int oc = blockIdx.x;

    float gv[4] = {0.f, 0.f, 0.f, 0.f};
#pragma unroll
    for (int k = 0; k < NCHUNK; ++k) {
        float v[4];
        *(float4*)v = *(const float4*)&partial2[k * 1024 + t * 4];
#pragma unroll
        for (int j = 0; j < 4; ++j) gv[j] += v[j];
    }

    for (int i = t; i < 1296; i += 256) G_pad[i] = 0.f;
    for (int i = t; i < 7056; i += 256) y1p[i] = 0.f;
    if (t < 144) sw2[t] = w2[t];
    if (t >= 160 && t < 176)      sp2[t - 160]      = b2[t - 160];
    else if (t >= 176 && t < 192) sp2[t - 160]      = g2[t - 176];
    else if (t >= 192 && t < 208) sp2[t - 160]      = bt2[t - 192];
    __syncthreads();

#pragma unroll
    for (int j = 0; j < 4; ++j) {
        const int e = t * 4 + j;
        G_pad[((e >> 5) + 2) * 36 + (e & 31) + 2] = gv[j];
    }
    __syncthreads();

    for (int idx = t; idx < 16 * 289; idx += 256) {
        const int c2 = idx / 289;
        const int r  = idx - c2 * 289;
        const int oy = r / 17, ox = r - (r / 17) * 17;
        const float* gp = &G_pad[(2 * oy) * 36 + 2 * ox];
        const float* wr = &sw2[c2 * 9];
        float s = sp2[c2];
#pragma unroll
        for (int ky = 0; ky < 3; ++ky)
#pragma unroll
            for (int kx = 0; kx < 3; ++kx)
                s = fmaf(gp[ky * 36 + kx], wr[ky * 3 + kx], s);
        y1[idx] = s;
    }
    __syncthreads();

    {
        const int lane = t & 63;
        const int ch   = (t >> 6) * 4 + (lane >> 4);
        const int j    = lane & 15;
        float s = 0.f, ss = 0.f;
        for (int i = j; i < 289; i += 16) {
            float v = y1[ch * 289 + i];
            s += v; ss += v * v;
        }
#pragma unroll
        for (int o = 8; o; o >>= 1) { s += __shfl_xor(s, o); ss += __shfl_xor(ss, o); }
        if (j == 0) {
            float m = s * (1.f / 289.f);
            float var = ss * (1.f / 289.f) - m * m;
            m1[ch] = m;
            r1[ch] = rsqrtf(var + 1e-5f);
        }
    }
    __syncthreads();

    for (int idx = t; idx < 16 * 289; idx += 256) {
        const int c2 = idx / 289;
        const int r  = idx - c2 * 289;
        const int oy = r / 17, ox = r - (r / 17) * 17;
        float v = (y1[idx] - m1[c2]) * r1[c2] * sp2[16 + c2] + sp2[32 + c2];
        y1p[c2 * 441 + (oy + 2) * 21 + ox + 2] = v > 0.f ? v : 0.f;
    }
    if (t >= 100 && t < 128) y2L[t] = 0.f;
    __syncthreads();

    {
        const int grp = t >> 7;
        const int px  = t & 127;
        if (px < 100) {
            const int oy = px / 10, ox = px - 10 * (px / 10);
            const float* wr = w3 + oc * 144 + grp * 72;
            float a0 = 0.f, a1 = 0.f, a2 = 0.f;
#pragma unroll
            for (int ic8 = 0; ic8 < 8; ++ic8) {
                const int ic = grp * 8 + ic8;
                const float* yi = &y1p[ic * 441 + (2 * oy) * 21 + 2 * ox];
                const float* wi = wr + ic8 * 9;
#pragma unroll
                for (int kx = 0; kx < 3; ++kx) {
                    a0 = fmaf(yi[kx],      wi[kx],     a0);
                    a1 = fmaf(yi[21 + kx], wi[3 + kx], a1);
                    a2 = fmaf(yi[42 + kx], wi[6 + kx], a2);
                }
            }
            y2L[grp * 128 + px] = (a0 + a1) + a2;
        }
    }
    __syncthreads();

    if (t < 100) y2L[t] = y2L[t] + y2L[128 + t] + b3[oc];
    __syncthreads();

    if (t < 64) {
        const float x0 = y2L[t], x1 = y2L[t + 64];
        float s = x0 + x1, ss = x0 * x0 + x1 * x1;
#pragma unroll
        for (int o = 32; o; o >>= 1) { s += __shfl_xor(s, o); ss += __shfl_xor(ss, o); }
        const float m   = s * 0.01f;
        const float var = ss * 0.01f - m * m;
        const float rs  = rsqrtf(var + 1e-5f);
        const float gg  = g3[oc], bb = bt3[oc];
        float a = 0.f;
        if (t < 100) { float f = (x0 - m) * rs * gg + bb; a += f > 0.f ? f : 0.f; }
        if (t < 36)  { float f = (x1 - m) * rs * gg + bb; a += f > 0.f ? f : 0.f; }
#pragma unroll
        for (int o = 32; o; o >>= 1) a += __shfl_xor(a, o);
        if (t == 0) out[oc] = a * 0.01f;
    }
}

// ---------------------------------------------------------------------------
extern "C" void kernel_launch(void* const* d_in, const int* in_sizes, int n_in,
                              void* d_out, int out_size, void* d_ws, size_t ws_size,
                              hipStream_t stream)
{
    const float* x   = (const float*)d_in[0];
    const float* w1  = (const float*)d_in[1];
    const float* b1  = (const float*)d_in[2];
    const float* w2  = (const float*)d_in[3];
    const float* b2  = (const float*)d_in[4];
    const float* g2  = (const float*)d_in[5];
    const float* bt2 = (const float*)d_in[6];
    const float* w3  = (const float*)d_in[7];
    const float* b3  = (const float*)d_in[8];
    const float* g3  = (const float*)d_in[9];
    const float* bt3 = (const float*)d_in[10];

    size_t cap = ws_size / 4096;               // 1024-float slots available
    int nblk = NBLK;
    if ((size_t)(nblk + NCHUNK) > cap) nblk = ((int)cap - NCHUNK) & ~7;
    if (nblk > NBLK) nblk = NBLK;
    if (nblk < 256) nblk = 256;

    float* P   = (float*)d_ws;                  // [nblk][1024]
    float* P2  = P + (size_t)nblk * 1024;       // [NCHUNK][1024]
    float* out = (float*)d_out;

    k_conv_gram<<<nblk, 512, 0, stream>>>(x, w1, b1, P, nblk);
    k_reduce<<<128, 256, 0, stream>>>(P, P2, nblk);
    k_tail2<<<32, 256, 0, stream>>>(P2, w2, b2, g2, bt2, w3, b3, g3, bt3, out);
}